// Round 11
// baseline (173.271 us; speedup 1.0000x reference)
//
#include <hip/hip_runtime.h>

typedef unsigned short u16;
typedef __attribute__((ext_vector_type(8))) _Float16 f16x8;
typedef __attribute__((ext_vector_type(2))) _Float16 f16x2;
typedef __attribute__((ext_vector_type(4))) float f32x4;

#define DEV static __device__ __forceinline__

DEV float bf2f(u16 h){ unsigned u = ((unsigned)h) << 16; return __builtin_bit_cast(float, u); }
DEV u16 f2bf(float f){ unsigned u = __builtin_bit_cast(unsigned, f); u += 0x7FFFu + ((u >> 16) & 1u); return (u16)(u >> 16); }
DEV u16 f2h(float f){ _Float16 h = (_Float16)f; return __builtin_bit_cast(u16, h); }
DEV float h2f(u16 h){ return (float)__builtin_bit_cast(_Float16, h); }

DEV f32x4 mfma16(f16x8 a, f16x8 b, f32x4 c){
  return __builtin_amdgcn_mfma_f32_16x16x32_f16(a, b, c, 0, 0, 0);
}

// relu(S1+R1) on 8 packed halves: 4x v_pk_add_f16 + 4x v_pk_max_f16.
DEV f16x8 build_frag(uint4 s, uint4 r){
  f16x8 a = __builtin_bit_cast(f16x8, s);
  f16x8 b = __builtin_bit_cast(f16x8, r);
  f16x8 v = a + b;
  const f16x8 z = {0,0,0,0,0,0,0,0};
  return __builtin_elementwise_max(v, z);
}

// Per-kernel dtype sniff: one L2-hot 256B read + wave ballot, wave-uniform.
DEV int sniff_isbf(const void* x){
  int l = threadIdx.x & 63;
  u16 u = ((const u16*)x)[2 * l];
  int e = (u >> 7) & 0xFF;
  int ok = (e >= 103 && e <= 143) ? 1 : 0;
  unsigned long long m = __ballot(ok);
  return (__builtin_popcountll(m) >= 40) ? 1 : 0;  // 1 = bf16 I/O
}

DEV float ldin(const void* p, int i, int isbf){
  return isbf ? bf2f(((const u16*)p)[i]) : ((const float*)p)[i];
}

DEV unsigned pk2(float a, float b){ return (unsigned)f2h(a) | ((unsigned)f2h(b) << 16); }
DEV unsigned pkbf(unsigned w){
  float lo = bf2f((u16)(w & 0xffff)), hi = bf2f((u16)(w >> 16));
  return pk2(lo, hi);
}
// load 8 source elements (group index g of 8) as 8 packed f16
DEV uint4 ld8f16(const void* p, int g, int isbf){
  uint4 r;
  if(isbf){
    uint4 v = ((const uint4*)p)[g];
    r.x = pkbf(v.x); r.y = pkbf(v.y); r.z = pkbf(v.z); r.w = pkbf(v.w);
  } else {
    float4 a = ((const float4*)p)[2*g], b4 = ((const float4*)p)[2*g + 1];
    r.x = pk2(a.x, a.y); r.y = pk2(a.z, a.w); r.z = pk2(b4.x, b4.y); r.w = pk2(b4.z, b4.w);
  }
  return r;
}

// Sizes: B=64, N=64, F=64, H=256, O=64, T=4, E=4032
// ws layout (bytes): W1T@256 | W2T@262400 | OW1T@393472 | OW2T@459008
//  | OW3T@590080 | S1@3215360 | R1@11603968 | AGG(f32)@19992576
#define OFF_W1T  256
#define OFF_W2T  262400
#define OFF_OW1T 393472
#define OFF_OW2T 459008
#define OFF_OW3T 590080
#define OFF_S1   3215360
#define OFF_R1   11603968
#define OFF_AGG  19992576

// ---------------- K0: tiled transpose+convert for the 5 weight matrices ----------------
__global__ __launch_bounds__(256) void k_tr(const void* __restrict__ x, const void* __restrict__ w1,
    const void* __restrict__ w2, const void* __restrict__ ow1, const void* __restrict__ ow2,
    const void* __restrict__ ow3, char* __restrict__ ws){
  const int isbf = sniff_isbf(x);
  __shared__ float tile[32][33];
  int bid = blockIdx.x, tid = threadIdx.x;
  const void* src; u16* dst; int R, C, off, r0, c0;
  if(bid < 128){ int g = bid >> 5, tt = bid & 31;
    src = w1; dst = (u16*)(ws + OFF_W1T); R = 128; C = 256; off = g * 32768;
    r0 = (tt >> 3) << 5; c0 = (tt & 7) << 5;
  } else if(bid < 192){ int bb = bid - 128; int g = bb >> 4, tt = bb & 15;
    src = w2; dst = (u16*)(ws + OFF_W2T); R = 256; C = 64; off = g * 16384;
    r0 = (tt >> 1) << 5; c0 = (tt & 1) << 5;
  } else if(bid < 224){ int bb = bid - 192;
    src = ow1; dst = (u16*)(ws + OFF_OW1T); R = 128; C = 256; off = 0;
    r0 = (bb >> 3) << 5; c0 = (bb & 7) << 5;
  } else if(bid < 288){ int bb = bid - 224;
    src = ow2; dst = (u16*)(ws + OFF_OW2T); R = 256; C = 256; off = 0;
    r0 = (bb >> 3) << 5; c0 = (bb & 7) << 5;
  } else { int bb = bid - 288;
    src = ow3; dst = (u16*)(ws + OFF_OW3T); R = 256; C = 64; off = 0;
    r0 = (bb >> 1) << 5; c0 = (bb & 1) << 5;
  }
  int tx = tid & 31, ty = tid >> 5;
  #pragma unroll
  for(int p = 0; p < 4; ++p){
    int r = ty + p * 8;
    tile[r][tx] = ldin(src, off + (r0 + r) * C + c0 + tx, isbf);
  }
  __syncthreads();
  #pragma unroll
  for(int p = 0; p < 4; ++p){
    int c = ty + p * 8;
    dst[off + (c0 + c) * R + r0 + tx] = f2h(tile[tx][c]);
  }
}

// ---------------- K1: S1/R1 = x @ w1-half (+b1 on receiver half) ----------------
// R8 epilogue (R9's sO staging was measured neutral-negative). x converted
// inline; b1 read raw.
__global__ __launch_bounds__(256) void k_s1r1(const void* __restrict__ x, const u16* __restrict__ W1T,
    const void* __restrict__ b1, u16* __restrict__ S1, u16* __restrict__ R1){
  __shared__ __align__(16) u16 sX[64][72];
  __shared__ __align__(16) u16 sW[256][72];
  const int tid = threadIdx.x, bid = blockIdx.x;
  const int b = bid & 63, th = bid >> 6, t = th >> 1, half = th & 1;
  const int isbf = sniff_isbf(x);
  {
    #pragma unroll
    for(int it=0; it<2; ++it){
      int c = tid + it*256; int row = c >> 3, col = (c & 7) * 8;
      *(uint4*)&sX[row][col] = ld8f16(x, b*512 + c, isbf);
    }
    const u16* base = W1T + t*32768 + half*64;
    #pragma unroll
    for(int it=0; it<8; ++it){
      int c = tid + it*256; int h = c >> 3, kc = (c & 7) * 8;
      *(uint4*)&sW[h][kc] = *(const uint4*)(base + h*128 + kc);
    }
  }
  __syncthreads();
  const int wv = tid >> 6, l = tid & 63, ml = l & 15, q = l >> 4;
  const f32x4 z = {0.f,0.f,0.f,0.f};
  f32x4 acc[4][4];
  #pragma unroll
  for(int mt=0;mt<4;++mt){ acc[mt][0]=z; acc[mt][1]=z; acc[mt][2]=z; acc[mt][3]=z; }
  #pragma unroll
  for(int ks=0; ks<2; ++ks){
    const int kb = ks*32 + q*8;
    f16x8 af[4], bff[4];
    #pragma unroll
    for(int mt=0;mt<4;++mt) af[mt] = *(const f16x8*)&sX[mt*16 + ml][kb];
    #pragma unroll
    for(int nt=0;nt<4;++nt) bff[nt] = *(const f16x8*)&sW[wv*64 + nt*16 + ml][kb];
    #pragma unroll
    for(int mt=0;mt<4;++mt)
      #pragma unroll
      for(int nt=0;nt<4;++nt)
        acc[mt][nt] = mfma16(af[mt], bff[nt], acc[mt][nt]);
  }
  u16* dst = (half ? R1 : S1) + (t*64 + b)*16384;
  #pragma unroll
  for(int nt=0;nt<4;++nt){
    const int h = wv*64 + nt*16 + ml;
    const float bias = half ? ldin(b1, t*256 + h, isbf) : 0.0f;
    #pragma unroll
    for(int mt=0;mt<4;++mt)
      #pragma unroll
      for(int r=0;r<4;++r){
        int irow = mt*16 + q*4 + r;
        dst[irow*256 + h] = f2h(acc[mt][nt][r] + bias);
      }
  }
}

// ---------------- K2: per-edge layer-2 + weighted receiver aggregation ----------------
// R10 (resubmitted after container failure): 2-receiver software pipeline on
// the R3 base. Measured 8400cy/jj vs ~1500-2500 modeled => the serial
// {MFMA -> drain -> epilogue VALU+atomics} chain per receiver is the exposed
// latency. Pipeline: compute accB(jjB), THEN epilogueA(jjA) -- its VALU
// depends only on drained accA, so it executes while accB's matrix work is
// in flight; symmetric for next accA vs epilogueB. ru in registers with
// natural A/B ping-pong; no lambdas, all static indexing.
// grid 256: block = (b, group of 16 receivers). wave = edge type t.
#define EDGE_COMPUTE(ACC, RU)                                              \
  {                                                                        \
    _Pragma("unroll")                                                      \
    for(int mt=0;mt<4;++mt){                                               \
      ACC[mt][0]=bini[0]; ACC[mt][1]=bini[1];                              \
      ACC[mt][2]=bini[2]; ACC[mt][3]=bini[3];                              \
    }                                                                      \
    _Pragma("unroll")                                                      \
    for(int ks=0;ks<8;++ks){                                               \
      _Pragma("unroll")                                                    \
      for(int mt=0;mt<4;++mt){                                             \
        f16x8 af = build_frag(su[mt][ks], RU[ks]);                         \
        _Pragma("unroll")                                                  \
        for(int nt=0;nt<4;++nt)                                            \
          ACC[mt][nt] = mfma16(af, bfr[nt][ks], ACC[mt][nt]);              \
      }                                                                    \
    }                                                                      \
  }

#define EDGE_EPI(ACC, JJ)                                                  \
  {                                                                        \
    float cs0=0.f, cs1=0.f, cs2=0.f, cs3=0.f;                              \
    _Pragma("unroll")                                                      \
    for(int mt=0;mt<4;++mt){                                               \
      const f32x4 rw4 = *(const f32x4*)&sRTa[t][JJ][mt*16 + q*4];          \
      _Pragma("unroll")                                                    \
      for(int r=0;r<4;++r){                                                \
        cs0 += fmaxf(ACC[mt][0][r], 0.0f) * rw4[r];                        \
        cs1 += fmaxf(ACC[mt][1][r], 0.0f) * rw4[r];                        \
        cs2 += fmaxf(ACC[mt][2][r], 0.0f) * rw4[r];                        \
        cs3 += fmaxf(ACC[mt][3][r], 0.0f) * rw4[r];                        \
      }                                                                    \
    }                                                                      \
    atomicAdd(&sAggB[(JJ)*64 +  0 + ml], cs0);                             \
    atomicAdd(&sAggB[(JJ)*64 + 16 + ml], cs1);                             \
    atomicAdd(&sAggB[(JJ)*64 + 32 + ml], cs2);                             \
    atomicAdd(&sAggB[(JJ)*64 + 48 + ml], cs3);                             \
  }

#define EDGE_LOADRU(RU, ROW)                                               \
  {                                                                        \
    const u16* r1r_ = r1b + (j0 + (ROW))*256;                              \
    _Pragma("unroll")                                                      \
    for(int ks=0;ks<8;++ks)                                                \
      RU[ks] = *(const uint4*)(r1r_ + ks*32 + q*8);                        \
  }

__global__ __launch_bounds__(256, 1) void k_edge(const void* __restrict__ x, const void* __restrict__ rt,
    const u16* __restrict__ W2T, const void* __restrict__ b2,
    const u16* __restrict__ S1, const u16* __restrict__ R1, float* __restrict__ AGG){
  __shared__ float sRTa[4][16][64];
  __shared__ float sAggB[1024];
  const int tid = threadIdx.x;
  const int t = tid >> 6, l = tid & 63, ml = l & 15, q = l >> 4;
  const int b = blockIdx.x >> 2, j0 = (blockIdx.x & 3) * 16;
  const int isbf = sniff_isbf(x);
  #pragma unroll
  for(int it=0; it<4; ++it) sAggB[it*256 + tid] = 0.0f;
  // this block's 16 receivers' rel_type weights (per-wave, same-wave use)
  #pragma unroll 1
  for(int jj=0; jj<16; ++jj){
    int j = j0 + jj, i = l;
    float v = 0.0f;
    if(i != j){ int e = i*63 + j - (j > i ? 1 : 0); v = ldin(rt, (b*4032 + e)*4 + t, isbf); }
    sRTa[t][jj][i] = v;
  }
  __syncthreads();          // covers sAggB zero-init
  f16x8 bfr[4][8];          // whole w2T[t]: 128 VGPRs
  {
    const u16* w2t = W2T + t*16384;
    #pragma unroll
    for(int nt=0;nt<4;++nt)
      #pragma unroll
      for(int ks=0;ks<8;++ks)
        bfr[nt][ks] = *(const f16x8*)(w2t + (nt*16 + ml)*256 + ks*32 + q*8);
  }
  uint4 su[4][8];           // whole S1[t][b] A-side: 128 VGPRs, loaded ONCE
  const u16* s1b = S1 + (t*64 + b)*16384;
  #pragma unroll
  for(int mt=0;mt<4;++mt)
    #pragma unroll
    for(int ks=0;ks<8;++ks)
      su[mt][ks] = *(const uint4*)(s1b + (mt*16 + ml)*256 + ks*32 + q*8);
  f32x4 bini[4];            // bias2 pre-folded into acc init
  #pragma unroll
  for(int nt=0;nt<4;++nt){
    float bv = ldin(b2, t*64 + nt*16 + ml, isbf);
    bini[nt].x = bv; bini[nt].y = bv; bini[nt].z = bv; bini[nt].w = bv;
  }
  const u16* r1b = R1 + (t*64 + b)*16384;
  uint4 ruA[8], ruB[8];
  f32x4 accA[4][4], accB[4][4];
  EDGE_LOADRU(ruA, 0)
  EDGE_LOADRU(ruB, 1)
  EDGE_COMPUTE(accA, ruA)           // prologue: acc for receiver 0 in flight
  #pragma unroll 1
  for(int jp=0; jp<8; ++jp){
    const int jjA = 2*jp, jjB = 2*jp + 1;
    EDGE_COMPUTE(accB, ruB)         // issue B's MFMAs
    if(jp < 7) EDGE_LOADRU(ruA, jjA + 2)   // prefetch next A row (ruA free)
    EDGE_EPI(accA, jjA)             // VALU overlaps B's in-flight matrix work
    if(jp < 7){
      EDGE_COMPUTE(accA, ruA)       // issue next A's MFMAs
      EDGE_LOADRU(ruB, jjB + 2)     // prefetch next B row (ruB free)
    }
    EDGE_EPI(accB, jjB)             // overlaps next A's matrix work
  }
  __syncthreads();
  float* aggb = AGG + (b*64 + j0)*64;
  #pragma unroll
  for(int it=0; it<4; ++it) aggb[it*256 + tid] = sAggB[it*256 + tid];
}

// ---------------- K3: node MLP (aug=[x,agg] -> 256 -> 256 -> 64) ----------------
// rows independent through the whole MLP -> 256 blocks (bb, row-group of 16).
__global__ __launch_bounds__(256) void k_node(const void* __restrict__ x, const float* __restrict__ AGG,
    const u16* __restrict__ OW1T, const void* __restrict__ ob1,
    const u16* __restrict__ OW2T, const void* __restrict__ ob2,
    const u16* __restrict__ OW3T, const void* __restrict__ ob3,
    void* __restrict__ out){
  __shared__ __align__(16) u16 sA[16][136];
  __shared__ __align__(16) u16 sH[16][264];
  __shared__ __align__(16) u16 sH2[16][264];
  __shared__ __align__(16) u16 sW[64][264];
  const int tid = threadIdx.x;
  const int bb = blockIdx.x >> 2, rg = blockIdx.x & 3;
  const int isbf = sniff_isbf(x);
  {
    if(tid < 128){           // x part: 16 rows x 64 cols = 128 groups of 8
      int row = tid >> 3, gc = tid & 7;
      *(uint4*)&sA[row][gc*8] = ld8f16(x, bb*512 + (rg*16 + row)*8 + gc, isbf);
    }
    const float* ag = AGG + bb*4096;
    #pragma unroll
    for(int it=0; it<4; ++it){
      int c = tid + it*256; int row = c >> 6, col = c & 63;
      sA[row][64 + col] = f2h(ag[(rg*16 + row)*64 + col]);
    }
  }
  const int wv = tid >> 6, l = tid & 63, ml = l & 15, q = l >> 4;
  const f32x4 z = {0.f,0.f,0.f,0.f};
  __syncthreads();
  for(int nc=0; nc<4; ++nc){
    #pragma unroll
    for(int it=0; it<4; ++it){
      int c = tid + it*256; int h = c >> 4, kc = (c & 15)*8;
      *(uint4*)&sW[h][kc] = *(const uint4*)(OW1T + (nc*64 + h)*128 + kc);
    }
    __syncthreads();
    f32x4 acc = z;
    #pragma unroll
    for(int ks=0; ks<4; ++ks){
      int kb = ks*32 + q*8;
      f16x8 bfrag = *(const f16x8*)&sW[wv*16 + ml][kb];
      f16x8 afrag = *(const f16x8*)&sA[ml][kb];
      acc = mfma16(afrag, bfrag, acc);
    }
    const int h = nc*64 + wv*16 + ml;
    const float bias = ldin(ob1, h, isbf);
    #pragma unroll
    for(int r=0;r<4;++r)
      sH[q*4 + r][h] = f2h(fmaxf(acc[r] + bias, 0.0f));
    __syncthreads();
  }
  for(int nc=0; nc<4; ++nc){
    #pragma unroll
    for(int it=0; it<8; ++it){
      int c = tid + it*256; int h = c >> 5, kc = (c & 31)*8;
      *(uint4*)&sW[h][kc] = *(const uint4*)(OW2T + (nc*64 + h)*256 + kc);
    }
    __syncthreads();
    f32x4 acc = z;
    #pragma unroll
    for(int ks=0; ks<8; ++ks){
      int kb = ks*32 + q*8;
      f16x8 bfrag = *(const f16x8*)&sW[wv*16 + ml][kb];
      f16x8 afrag = *(const f16x8*)&sH[ml][kb];
      acc = mfma16(afrag, bfrag, acc);
    }
    const int h = nc*64 + wv*16 + ml;
    const float bias = ldin(ob2, h, isbf);
    #pragma unroll
    for(int r=0;r<4;++r)
      sH2[q*4 + r][h] = f2h(fmaxf(acc[r] + bias, 0.0f));
    __syncthreads();
  }
  {
    #pragma unroll
    for(int it=0; it<8; ++it){
      int c = tid + it*256; int h = c >> 5, kc = (c & 31)*8;
      *(uint4*)&sW[h][kc] = *(const uint4*)(OW3T + h*256 + kc);
    }
    __syncthreads();
    f32x4 acc = z;
    #pragma unroll
    for(int ks=0; ks<8; ++ks){
      int kb = ks*32 + q*8;
      f16x8 bfrag = *(const f16x8*)&sW[wv*16 + ml][kb];
      f16x8 afrag = *(const f16x8*)&sH2[ml][kb];
      acc = mfma16(afrag, bfrag, acc);
    }
    const int o = wv*16 + ml;
    const float bias = ldin(ob3, o, isbf);
    #pragma unroll
    for(int r=0;r<4;++r){
      int row = rg*16 + q*4 + r;
      float v = acc[r] + bias;
      int idx = bb*4096 + row*64 + o;
      if(isbf) ((u16*)out)[idx] = f2bf(v);
      else     ((float*)out)[idx] = v;
    }
  }
}

extern "C" void kernel_launch(void* const* d_in, const int* in_sizes, int n_in,
                              void* d_out, int out_size, void* d_ws, size_t ws_size,
                              hipStream_t stream){
  (void)in_sizes; (void)n_in; (void)out_size; (void)ws_size;
  char* ws = (char*)d_ws;
  u16* W1T  = (u16*)(ws + OFF_W1T);
  u16* W2T  = (u16*)(ws + OFF_W2T);
  u16* OW1T = (u16*)(ws + OFF_OW1T);
  u16* OW2T = (u16*)(ws + OFF_OW2T);
  u16* OW3T = (u16*)(ws + OFF_OW3T);
  u16* S1   = (u16*)(ws + OFF_S1);
  u16* R1   = (u16*)(ws + OFF_R1);
  float* AGG = (float*)(ws + OFF_AGG);

  k_tr<<<304, 256, 0, stream>>>(d_in[0], d_in[4], d_in[6], d_in[8], d_in[10], d_in[12], ws);
  k_s1r1<<<512, 256, 0, stream>>>(d_in[0], W1T, d_in[5], S1, R1);
  k_edge<<<256, 256, 0, stream>>>(d_in[0], d_in[1], W2T, d_in[7], S1, R1, AGG);
  k_node<<<256, 256, 0, stream>>>(d_in[0], AGG, OW1T, d_in[9], OW2T, d_in[11], OW3T, d_in[13], d_out);
}

// Round 12
// 155.959 us; speedup vs baseline: 1.1110x; 1.1110x over previous
//
#include <hip/hip_runtime.h>

typedef unsigned short u16;
typedef __attribute__((ext_vector_type(8))) _Float16 f16x8;
typedef __attribute__((ext_vector_type(2))) _Float16 f16x2;
typedef __attribute__((ext_vector_type(4))) float f32x4;

#define DEV static __device__ __forceinline__

DEV float bf2f(u16 h){ unsigned u = ((unsigned)h) << 16; return __builtin_bit_cast(float, u); }
DEV u16 f2bf(float f){ unsigned u = __builtin_bit_cast(unsigned, f); u += 0x7FFFu + ((u >> 16) & 1u); return (u16)(u >> 16); }
DEV u16 f2h(float f){ _Float16 h = (_Float16)f; return __builtin_bit_cast(u16, h); }
DEV float h2f(u16 h){ return (float)__builtin_bit_cast(_Float16, h); }

DEV f32x4 mfma16(f16x8 a, f16x8 b, f32x4 c){
  return __builtin_amdgcn_mfma_f32_16x16x32_f16(a, b, c, 0, 0, 0);
}

// relu(S1+R1) on 8 packed halves: 4x v_pk_add_f16 + 4x v_pk_max_f16.
DEV f16x8 build_frag(uint4 s, uint4 r){
  f16x8 a = __builtin_bit_cast(f16x8, s);
  f16x8 b = __builtin_bit_cast(f16x8, r);
  f16x8 v = a + b;
  const f16x8 z = {0,0,0,0,0,0,0,0};
  return __builtin_elementwise_max(v, z);
}

// Per-kernel dtype sniff: one L2-hot 256B read + wave ballot, wave-uniform.
DEV int sniff_isbf(const void* x){
  int l = threadIdx.x & 63;
  u16 u = ((const u16*)x)[2 * l];
  int e = (u >> 7) & 0xFF;
  int ok = (e >= 103 && e <= 143) ? 1 : 0;
  unsigned long long m = __ballot(ok);
  return (__builtin_popcountll(m) >= 40) ? 1 : 0;  // 1 = bf16 I/O
}

DEV float ldin(const void* p, int i, int isbf){
  return isbf ? bf2f(((const u16*)p)[i]) : ((const float*)p)[i];
}

DEV unsigned pk2(float a, float b){ return (unsigned)f2h(a) | ((unsigned)f2h(b) << 16); }
DEV unsigned pkbf(unsigned w){
  float lo = bf2f((u16)(w & 0xffff)), hi = bf2f((u16)(w >> 16));
  return pk2(lo, hi);
}
// load 8 source elements (group index g of 8) as 8 packed f16
DEV uint4 ld8f16(const void* p, int g, int isbf){
  uint4 r;
  if(isbf){
    uint4 v = ((const uint4*)p)[g];
    r.x = pkbf(v.x); r.y = pkbf(v.y); r.z = pkbf(v.z); r.w = pkbf(v.w);
  } else {
    float4 a = ((const float4*)p)[2*g], b4 = ((const float4*)p)[2*g + 1];
    r.x = pk2(a.x, a.y); r.y = pk2(a.z, a.w); r.z = pk2(b4.x, b4.y); r.w = pk2(b4.z, b4.w);
  }
  return r;
}

// Sizes: B=64, N=64, F=64, H=256, O=64, T=4, E=4032
// ws layout (bytes): W1T@256 | W2T@262400 | OW1T@393472 | OW2T@459008
//  | OW3T@590080 | S1@3215360 | R1@11603968 | AGG(f32)@19992576
#define OFF_W1T  256
#define OFF_W2T  262400
#define OFF_OW1T 393472
#define OFF_OW2T 459008
#define OFF_OW3T 590080
#define OFF_S1   3215360
#define OFF_R1   11603968
#define OFF_AGG  19992576

// ---------------- K0: tiled transpose+convert for the 5 weight matrices ----------------
__global__ __launch_bounds__(256) void k_tr(const void* __restrict__ x, const void* __restrict__ w1,
    const void* __restrict__ w2, const void* __restrict__ ow1, const void* __restrict__ ow2,
    const void* __restrict__ ow3, char* __restrict__ ws){
  const int isbf = sniff_isbf(x);
  __shared__ float tile[32][33];
  int bid = blockIdx.x, tid = threadIdx.x;
  const void* src; u16* dst; int R, C, off, r0, c0;
  if(bid < 128){ int g = bid >> 5, tt = bid & 31;
    src = w1; dst = (u16*)(ws + OFF_W1T); R = 128; C = 256; off = g * 32768;
    r0 = (tt >> 3) << 5; c0 = (tt & 7) << 5;
  } else if(bid < 192){ int bb = bid - 128; int g = bb >> 4, tt = bb & 15;
    src = w2; dst = (u16*)(ws + OFF_W2T); R = 256; C = 64; off = g * 16384;
    r0 = (tt >> 1) << 5; c0 = (tt & 1) << 5;
  } else if(bid < 224){ int bb = bid - 192;
    src = ow1; dst = (u16*)(ws + OFF_OW1T); R = 128; C = 256; off = 0;
    r0 = (bb >> 3) << 5; c0 = (bb & 7) << 5;
  } else if(bid < 288){ int bb = bid - 224;
    src = ow2; dst = (u16*)(ws + OFF_OW2T); R = 256; C = 256; off = 0;
    r0 = (bb >> 3) << 5; c0 = (bb & 7) << 5;
  } else { int bb = bid - 288;
    src = ow3; dst = (u16*)(ws + OFF_OW3T); R = 256; C = 64; off = 0;
    r0 = (bb >> 1) << 5; c0 = (bb & 1) << 5;
  }
  int tx = tid & 31, ty = tid >> 5;
  #pragma unroll
  for(int p = 0; p < 4; ++p){
    int r = ty + p * 8;
    tile[r][tx] = ldin(src, off + (r0 + r) * C + c0 + tx, isbf);
  }
  __syncthreads();
  #pragma unroll
  for(int p = 0; p < 4; ++p){
    int c = ty + p * 8;
    dst[off + (c0 + c) * R + r0 + tx] = f2h(tile[tx][c]);
  }
}

// ---------------- K1: S1/R1 = x @ w1-half (+b1 on receiver half) ----------------
// x converted inline during sX staging; b1 read raw.
__global__ __launch_bounds__(256) void k_s1r1(const void* __restrict__ x, const u16* __restrict__ W1T,
    const void* __restrict__ b1, u16* __restrict__ S1, u16* __restrict__ R1){
  __shared__ __align__(16) u16 sX[64][72];
  __shared__ __align__(16) u16 sW[256][72];
  const int tid = threadIdx.x, bid = blockIdx.x;
  const int b = bid & 63, th = bid >> 6, t = th >> 1, half = th & 1;
  const int isbf = sniff_isbf(x);
  {
    #pragma unroll
    for(int it=0; it<2; ++it){
      int c = tid + it*256; int row = c >> 3, col = (c & 7) * 8;
      *(uint4*)&sX[row][col] = ld8f16(x, b*512 + c, isbf);
    }
    const u16* base = W1T + t*32768 + half*64;
    #pragma unroll
    for(int it=0; it<8; ++it){
      int c = tid + it*256; int h = c >> 3, kc = (c & 7) * 8;
      *(uint4*)&sW[h][kc] = *(const uint4*)(base + h*128 + kc);
    }
  }
  __syncthreads();
  const int wv = tid >> 6, l = tid & 63, ml = l & 15, q = l >> 4;
  const f32x4 z = {0.f,0.f,0.f,0.f};
  f32x4 acc[4][4];
  #pragma unroll
  for(int mt=0;mt<4;++mt){ acc[mt][0]=z; acc[mt][1]=z; acc[mt][2]=z; acc[mt][3]=z; }
  #pragma unroll
  for(int ks=0; ks<2; ++ks){
    const int kb = ks*32 + q*8;
    f16x8 af[4], bff[4];
    #pragma unroll
    for(int mt=0;mt<4;++mt) af[mt] = *(const f16x8*)&sX[mt*16 + ml][kb];
    #pragma unroll
    for(int nt=0;nt<4;++nt) bff[nt] = *(const f16x8*)&sW[wv*64 + nt*16 + ml][kb];
    #pragma unroll
    for(int mt=0;mt<4;++mt)
      #pragma unroll
      for(int nt=0;nt<4;++nt)
        acc[mt][nt] = mfma16(af[mt], bff[nt], acc[mt][nt]);
  }
  u16* dst = (half ? R1 : S1) + (t*64 + b)*16384;
  #pragma unroll
  for(int nt=0;nt<4;++nt){
    const int h = wv*64 + nt*16 + ml;
    const float bias = half ? ldin(b1, t*256 + h, isbf) : 0.0f;
    #pragma unroll
    for(int mt=0;mt<4;++mt)
      #pragma unroll
      for(int r=0;r<4;++r){
        int irow = mt*16 + q*4 + r;
        dst[irow*256 + h] = f2h(acc[mt][nt][r] + bias);
      }
  }
}

// ---------------- K2: per-edge layer-2 + weighted receiver aggregation ----------------
// FINAL (R8 config, best measured 155.0us total / ~58.5us k_edge).
// Session record for this kernel, all counter-verified:
//  - R3 base: su+bfr register-resident (256 regs), 1 wave/SIMD, all-lane
//    LDS atomics, bias folded into acc init: 55.9-58.5us.
//  - more waves via launch_bounds (R1,R4,R5): VGPR cap -> su/bfr spill,
//    FETCH 23MB->450MB, ~2x slower.
//  - more waves via LDS-staged su + split bfr (R6): occupancy 2x but
//    duplicated frag-build VALU + DS pressure: 71.7us.
//  - 2-receiver in-loop ILP (R7): LDS reads exposed at ~490 live regs: 69.5us.
//  - 2-receiver epilogue-overlap pipeline (R11): 490-reg demand spilled
//    (WRITE 1->9.2MB): 75.9us.
// Conclusion: the residency that makes this kernel fast consumes exactly
// the register budget any latency-hiding scheme needs. Converged.
// grid 256: block = (b, group of 16 receivers). wave = edge type t.
__global__ __launch_bounds__(256, 1) void k_edge(const void* __restrict__ x, const void* __restrict__ rt,
    const u16* __restrict__ W2T, const void* __restrict__ b2,
    const u16* __restrict__ S1, const u16* __restrict__ R1, float* __restrict__ AGG){
  __shared__ float sRTa[4][16][64];
  __shared__ float sAggB[1024];
  const int tid = threadIdx.x;
  const int t = tid >> 6, l = tid & 63, ml = l & 15, q = l >> 4;
  const int b = blockIdx.x >> 2, j0 = (blockIdx.x & 3) * 16;
  const int isbf = sniff_isbf(x);
  #pragma unroll
  for(int it=0; it<4; ++it) sAggB[it*256 + tid] = 0.0f;
  // this block's 16 receivers' rel_type weights (per-wave, same-wave use)
  #pragma unroll 1
  for(int jj=0; jj<16; ++jj){
    int j = j0 + jj, i = l;
    float v = 0.0f;
    if(i != j){ int e = i*63 + j - (j > i ? 1 : 0); v = ldin(rt, (b*4032 + e)*4 + t, isbf); }
    sRTa[t][jj][i] = v;
  }
  __syncthreads();          // covers sAggB zero-init
  f16x8 bfr[4][8];          // whole w2T[t]: 128 VGPRs
  {
    const u16* w2t = W2T + t*16384;
    #pragma unroll
    for(int nt=0;nt<4;++nt)
      #pragma unroll
      for(int ks=0;ks<8;++ks)
        bfr[nt][ks] = *(const f16x8*)(w2t + (nt*16 + ml)*256 + ks*32 + q*8);
  }
  uint4 su[4][8];           // whole S1[t][b] A-side: 128 VGPRs, loaded ONCE
  const u16* s1b = S1 + (t*64 + b)*16384;
  #pragma unroll
  for(int mt=0;mt<4;++mt)
    #pragma unroll
    for(int ks=0;ks<8;++ks)
      su[mt][ks] = *(const uint4*)(s1b + (mt*16 + ml)*256 + ks*32 + q*8);
  f32x4 bini[4];            // bias2 pre-folded into acc init
  #pragma unroll
  for(int nt=0;nt<4;++nt){
    float bv = ldin(b2, t*64 + nt*16 + ml, isbf);
    bini[nt].x = bv; bini[nt].y = bv; bini[nt].z = bv; bini[nt].w = bv;
  }
  const u16* r1b = R1 + (t*64 + b)*16384;
  uint4 ru[8], run[8];
  #pragma unroll
  for(int ks=0;ks<8;++ks) ru[ks] = *(const uint4*)(r1b + j0*256 + ks*32 + q*8);
  #pragma unroll 1
  for(int jj=0; jj<16; ++jj){
    // hoisted LDS reads: this jj's 16 rel_type weights (4 rows per mt), b128 each
    f32x4 rw4[4];
    #pragma unroll
    for(int mt=0;mt<4;++mt) rw4[mt] = *(const f32x4*)&sRTa[t][jj][mt*16 + q*4];
    if(jj < 15){            // prefetch next receiver row while MFMAs run
      const u16* r1n = r1b + (j0 + jj + 1)*256;
      #pragma unroll
      for(int ks=0;ks<8;++ks) run[ks] = *(const uint4*)(r1n + ks*32 + q*8);
    }
    f32x4 acc[4][4];
    #pragma unroll
    for(int mt=0;mt<4;++mt){
      acc[mt][0]=bini[0]; acc[mt][1]=bini[1]; acc[mt][2]=bini[2]; acc[mt][3]=bini[3];
    }
    #pragma unroll
    for(int ks=0;ks<8;++ks){
      #pragma unroll
      for(int mt=0;mt<4;++mt){
        f16x8 af = build_frag(su[mt][ks], ru[ks]);   // relu(S1+R1) in-register
        #pragma unroll
        for(int nt=0;nt<4;++nt) acc[mt][nt] = mfma16(af, bfr[nt][ks], acc[mt][nt]);
      }
    }
    // epilogue: relu(C) (bias pre-folded), weighted column-sum over sender rows i
    float cs[4] = {0.f,0.f,0.f,0.f};
    #pragma unroll
    for(int mt=0;mt<4;++mt)
      #pragma unroll
      for(int nt=0;nt<4;++nt)
        #pragma unroll
        for(int r=0;r<4;++r)
          cs[nt] += fmaxf(acc[mt][nt][r], 0.0f) * rw4[mt][r];
    // all-lane fire-and-forget LDS atomic (4-way same-address conflict is
    // ~16 LDS slots vs ~1400cy of dependent shfl latency it replaces)
    #pragma unroll
    for(int nt=0;nt<4;++nt)
      atomicAdd(&sAggB[jj*64 + nt*16 + ml], cs[nt]);
    #pragma unroll
    for(int ks=0;ks<8;++ks) ru[ks] = run[ks];
  }
  __syncthreads();
  float* aggb = AGG + (b*64 + j0)*64;
  #pragma unroll
  for(int it=0; it<4; ++it) aggb[it*256 + tid] = sAggB[it*256 + tid];
}

// ---------------- K3: node MLP (aug=[x,agg] -> 256 -> 256 -> 64) ----------------
// rows independent through the whole MLP -> 256 blocks (bb, row-group of 16).
__global__ __launch_bounds__(256) void k_node(const void* __restrict__ x, const float* __restrict__ AGG,
    const u16* __restrict__ OW1T, const void* __restrict__ ob1,
    const u16* __restrict__ OW2T, const void* __restrict__ ob2,
    const u16* __restrict__ OW3T, const void* __restrict__ ob3,
    void* __restrict__ out){
  __shared__ __align__(16) u16 sA[16][136];
  __shared__ __align__(16) u16 sH[16][264];
  __shared__ __align__(16) u16 sH2[16][264];
  __shared__ __align__(16) u16 sW[64][264];
  const int tid = threadIdx.x;
  const int bb = blockIdx.x >> 2, rg = blockIdx.x & 3;
  const int isbf = sniff_isbf(x);
  {
    if(tid < 128){           // x part: 16 rows x 64 cols = 128 groups of 8
      int row = tid >> 3, gc = tid & 7;
      *(uint4*)&sA[row][gc*8] = ld8f16(x, bb*512 + (rg*16 + row)*8 + gc, isbf);
    }
    const float* ag = AGG + bb*4096;
    #pragma unroll
    for(int it=0; it<4; ++it){
      int c = tid + it*256; int row = c >> 6, col = c & 63;
      sA[row][64 + col] = f2h(ag[(rg*16 + row)*64 + col]);
    }
  }
  const int wv = tid >> 6, l = tid & 63, ml = l & 15, q = l >> 4;
  const f32x4 z = {0.f,0.f,0.f,0.f};
  __syncthreads();
  for(int nc=0; nc<4; ++nc){
    #pragma unroll
    for(int it=0; it<4; ++it){
      int c = tid + it*256; int h = c >> 4, kc = (c & 15)*8;
      *(uint4*)&sW[h][kc] = *(const uint4*)(OW1T + (nc*64 + h)*128 + kc);
    }
    __syncthreads();
    f32x4 acc = z;
    #pragma unroll
    for(int ks=0; ks<4; ++ks){
      int kb = ks*32 + q*8;
      f16x8 bfrag = *(const f16x8*)&sW[wv*16 + ml][kb];
      f16x8 afrag = *(const f16x8*)&sA[ml][kb];
      acc = mfma16(afrag, bfrag, acc);
    }
    const int h = nc*64 + wv*16 + ml;
    const float bias = ldin(ob1, h, isbf);
    #pragma unroll
    for(int r=0;r<4;++r)
      sH[q*4 + r][h] = f2h(fmaxf(acc[r] + bias, 0.0f));
    __syncthreads();
  }
  for(int nc=0; nc<4; ++nc){
    #pragma unroll
    for(int it=0; it<8; ++it){
      int c = tid + it*256; int h = c >> 5, kc = (c & 31)*8;
      *(uint4*)&sW[h][kc] = *(const uint4*)(OW2T + (nc*64 + h)*256 + kc);
    }
    __syncthreads();
    f32x4 acc = z;
    #pragma unroll
    for(int ks=0; ks<8; ++ks){
      int kb = ks*32 + q*8;
      f16x8 bfrag = *(const f16x8*)&sW[wv*16 + ml][kb];
      f16x8 afrag = *(const f16x8*)&sH[ml][kb];
      acc = mfma16(afrag, bfrag, acc);
    }
    const int h = nc*64 + wv*16 + ml;
    const float bias = ldin(ob2, h, isbf);
    #pragma unroll
    for(int r=0;r<4;++r)
      sH2[q*4 + r][h] = f2h(fmaxf(acc[r] + bias, 0.0f));
    __syncthreads();
  }
  {
    #pragma unroll
    for(int it=0; it<8; ++it){
      int c = tid + it*256; int h = c >> 5, kc = (c & 31)*8;
      *(uint4*)&sW[h][kc] = *(const uint4*)(OW3T + h*256 + kc);
    }
    __syncthreads();
    f32x4 acc = z;
    #pragma unroll
    for(int ks=0; ks<8; ++ks){
      int kb = ks*32 + q*8;
      f16x8 bfrag = *(const f16x8*)&sW[wv*16 + ml][kb];
      f16x8 afrag = *(const f16x8*)&sH2[ml][kb];
      acc = mfma16(afrag, bfrag, acc);
    }
    const int o = wv*16 + ml;
    const float bias = ldin(ob3, o, isbf);
    #pragma unroll
    for(int r=0;r<4;++r){
      int row = rg*16 + q*4 + r;
      float v = acc[r] + bias;
      int idx = bb*4096 + row*64 + o;
      if(isbf) ((u16*)out)[idx] = f2bf(v);
      else     ((float*)out)[idx] = v;
    }
  }
}

extern "C" void kernel_launch(void* const* d_in, const int* in_sizes, int n_in,
                              void* d_out, int out_size, void* d_ws, size_t ws_size,
                              hipStream_t stream){
  (void)in_sizes; (void)n_in; (void)out_size; (void)ws_size;
  char* ws = (char*)d_ws;
  u16* W1T  = (u16*)(ws + OFF_W1T);
  u16* W2T  = (u16*)(ws + OFF_W2T);
  u16* OW1T = (u16*)(ws + OFF_OW1T);
  u16* OW2T = (u16*)(ws + OFF_OW2T);
  u16* OW3T = (u16*)(ws + OFF_OW3T);
  u16* S1   = (u16*)(ws + OFF_S1);
  u16* R1   = (u16*)(ws + OFF_R1);
  float* AGG = (float*)(ws + OFF_AGG);

  k_tr<<<304, 256, 0, stream>>>(d_in[0], d_in[4], d_in[6], d_in[8], d_in[10], d_in[12], ws);
  k_s1r1<<<512, 256, 0, stream>>>(d_in[0], W1T, d_in[5], S1, R1);
  k_edge<<<256, 256, 0, stream>>>(d_in[0], d_in[1], W2T, d_in[7], S1, R1, AGG);
  k_node<<<256, 256, 0, stream>>>(d_in[0], AGG, OW1T, d_in[9], OW2T, d_in[11], OW3T, d_in[13], d_out);
}